// Round 5
// baseline (369.649 us; speedup 1.0000x reference)
//
#include <hip/hip_runtime.h>
#include <math.h>

#define D_ 8
#define H_ 64
#define IN_ 17
#define SLOPE_ 0.2f
#define B_ 128
#define T_ 514
#define W_ 512
#define N_ (B_*W_)            // 65536
#define RES_SZ (N_*D_)        // 524288
#define LOG_OFF RES_SZ        // 524288
#define HJ_OFF (RES_SZ + B_)  // 524416

#define P1S 84   // packed row: [W1T row (64) | W0 row (17) | b0 (1) | pad 2]
#define P2S 68   // packed row: [W2 row (64) | b2 | Wo | pad 2]
#define P2_OFF (D_*H_*P1S)

// Packs weights into row-contiguous records and zero-inits the logdet region.
__global__ void setup_kernel(const float* __restrict__ W0, const float* __restrict__ b0,
                             const float* __restrict__ W1, const float* __restrict__ W2,
                             const float* __restrict__ b2, const float* __restrict__ Wo,
                             float* __restrict__ ws, float* __restrict__ out) {
    int d = blockIdx.x;
    float* p1 = ws + d * H_ * P1S;
    float* p2 = ws + P2_OFF + d * H_ * P2S;
    for (int idx = threadIdx.x; idx < H_ * H_; idx += blockDim.x) {
        int r = idx >> 6, c = idx & 63;
        p1[r * P1S + c] = W1[(d * H_ + c) * H_ + r];   // W1T[r][c] = W1[d][c][r]
        p2[r * P2S + c] = W2[(d * H_ + r) * H_ + c];   // W2 row r
    }
    for (int r = threadIdx.x; r < H_; r += blockDim.x) {
        for (int i = 0; i < IN_; ++i)
            p1[r * P1S + 64 + i] = W0[(d * H_ + r) * IN_ + i];
        p1[r * P1S + 81] = b0[d * H_ + r];
        p2[r * P2S + 64] = b2[d * H_ + r];
        p2[r * P2S + 65] = Wo[d * H_ + r];
    }
    if (d == 0 && threadIdx.x < B_) out[LOG_OFF + threadIdx.x] = 0.0f;
}

// Weights staged in LDS per block; phase loops read rows with wave-uniform
// ds_read_b128 (broadcast, conflict-free, pipelinable) instead of s_load
// streams that thrash the 16KB scalar cache (R1-R4: 40%+ idle from lgkm
// stalls on L2-latency scalar loads).
__global__ __launch_bounds__(256) void mlp_kernel(
    const float* __restrict__ x,
    const float* __restrict__ b1g,
    const float* __restrict__ bo,
    const float* __restrict__ ws,
    float* __restrict__ out)
{
    __shared__ float sP1[H_ * P1S];   // 5376 floats
    __shared__ float sP2[H_ * P2S];   // 4352 floats
    __shared__ float sb1[H_];
    __shared__ float red[4];

    const int bid = blockIdx.x;
    const int d   = bid >> 8;          // 256 blocks per d
    const int rem = bid & 255;
    const int b   = rem >> 1;
    const int w   = ((rem & 1) << 8) | threadIdx.x;   // 0..511
    const int n   = b * W_ + w;

    // ---- stage packed weights into LDS (one-time per block)
    {
        const float4* g1 = (const float4*)(ws + d * H_ * P1S);
        const float4* g2 = (const float4*)(ws + P2_OFF + d * H_ * P2S);
        float4* l1 = (float4*)sP1;
        float4* l2 = (float4*)sP2;
        for (int i = threadIdx.x; i < H_ * P1S / 4; i += 256) l1[i] = g1[i];
        for (int i = threadIdx.x; i < H_ * P2S / 4; i += 256) l2[i] = g2[i];
        if (threadIdx.x < H_) sb1[threadIdx.x] = b1g[d * H_ + threadIdx.x];
    }

    // ---- gather window input while staging lands
    float inp[IN_];
    {
        const float* xp = x + (b * T_ + w) * D_;
        const float4* xp4 = (const float4*)xp;
        float4 q0 = xp4[0], q1 = xp4[1], q2 = xp4[2], q3 = xp4[3];
        inp[0]=q0.x;  inp[1]=q0.y;  inp[2]=q0.z;  inp[3]=q0.w;
        inp[4]=q1.x;  inp[5]=q1.y;  inp[6]=q1.z;  inp[7]=q1.w;
        inp[8]=q2.x;  inp[9]=q2.y;  inp[10]=q2.z; inp[11]=q2.w;
        inp[12]=q3.x; inp[13]=q3.y; inp[14]=q3.z; inp[15]=q3.w;
        inp[16] = xp[16 + d];
    }
    __syncthreads();

    // ---- Phase A: layer0 dot fused with layer1 outer-product
    float h1acc[H_];
#pragma unroll
    for (int g = 0; g < H_; ++g) h1acc[g] = sb1[g];

    unsigned long long m0 = 0ull;

#pragma unroll 2
    for (int h = 0; h < H_; ++h) {
        const float4* r4 = (const float4*)(sP1 + h * P1S);
        float4 wa = r4[16], wb = r4[17], wc = r4[18], wd = r4[19], wt = r4[20];
        float t0 = wt.y, t1 = 0.f, t2 = 0.f, t3 = 0.f;   // wt.y = b0
        t0 = fmaf(inp[0],  wa.x, t0); t1 = fmaf(inp[1],  wa.y, t1);
        t2 = fmaf(inp[2],  wa.z, t2); t3 = fmaf(inp[3],  wa.w, t3);
        t0 = fmaf(inp[4],  wb.x, t0); t1 = fmaf(inp[5],  wb.y, t1);
        t2 = fmaf(inp[6],  wb.z, t2); t3 = fmaf(inp[7],  wb.w, t3);
        t0 = fmaf(inp[8],  wc.x, t0); t1 = fmaf(inp[9],  wc.y, t1);
        t2 = fmaf(inp[10], wc.z, t2); t3 = fmaf(inp[11], wc.w, t3);
        t0 = fmaf(inp[12], wd.x, t0); t1 = fmaf(inp[13], wd.y, t1);
        t2 = fmaf(inp[14], wd.z, t2); t3 = fmaf(inp[15], wd.w, t3);
        t0 = fmaf(inp[16], wt.x, t0);
        float hv = (t0 + t2) + (t1 + t3);
        bool  p  = hv > 0.0f;
        float a0h = p ? hv : hv * SLOPE_;
        m0 |= ((unsigned long long)p) << h;
#pragma unroll
        for (int q = 0; q < 16; ++q) {
            float4 wv = r4[q];
            h1acc[4*q+0] = fmaf(a0h, wv.x, h1acc[4*q+0]);
            h1acc[4*q+1] = fmaf(a0h, wv.y, h1acc[4*q+1]);
            h1acc[4*q+2] = fmaf(a0h, wv.z, h1acc[4*q+2]);
            h1acc[4*q+3] = fmaf(a0h, wv.w, h1acc[4*q+3]);
        }
    }
    // inp dead.

    // ---- Phase B: leaky in place (sign preserved so m1 recoverable from h1acc)
#pragma unroll
    for (int g = 0; g < H_; ++g) {
        float hv = h1acc[g];
        h1acc[g] = hv > 0.0f ? hv : hv * SLOPE_;
    }

    // ---- Phase C (merged): layer2 dot + out-dot + backward-through-W2 outer product
    float g2acc[H_];
#pragma unroll
    for (int k = 0; k < H_; ++k) g2acc[k] = 0.0f;
    float outv = bo[d];

#pragma unroll 2
    for (int g = 0; g < H_; ++g) {
        const float4* r4 = (const float4*)(sP2 + g * P2S);
        float4 e = r4[16];                       // e.x = b2, e.y = Wo
        float t0 = e.x, t1 = 0.f, t2 = 0.f, t3 = 0.f;
#pragma unroll
        for (int q = 0; q < 16; ++q) {
            float4 wv = r4[q];
            t0 = fmaf(h1acc[4*q+0], wv.x, t0);
            t1 = fmaf(h1acc[4*q+1], wv.y, t1);
            t2 = fmaf(h1acc[4*q+2], wv.z, t2);
            t3 = fmaf(h1acc[4*q+3], wv.w, t3);
        }
        float hv = (t0 + t2) + (t1 + t3);
        bool  p  = hv > 0.0f;
        float a2g = p ? hv : hv * SLOPE_;
        float gb  = e.y * (p ? 1.0f : SLOPE_);
        outv = fmaf(e.y, a2g, outv);
#pragma unroll
        for (int q = 0; q < 16; ++q) {
            float4 wv = r4[q];
            g2acc[4*q+0] = fmaf(gb, wv.x, g2acc[4*q+0]);
            g2acc[4*q+1] = fmaf(gb, wv.y, g2acc[4*q+1]);
            g2acc[4*q+2] = fmaf(gb, wv.z, g2acc[4*q+2]);
            g2acc[4*q+3] = fmaf(gb, wv.w, g2acc[4*q+3]);
        }
    }

    out[n * D_ + d] = outv;   // residuals[b,w,d]

    // ---- Phase D: apply m1 (sign of pre-activation preserved in h1acc)
#pragma unroll
    for (int k = 0; k < H_; ++k)
        g2acc[k] *= (h1acc[k] > 0.0f ? 1.0f : SLOPE_);

    // ---- Phase E: backward through W1 (dot via W1T row) fused with jac outer (W0 row)
    float jac[IN_];
#pragma unroll
    for (int i = 0; i < IN_; ++i) jac[i] = 0.0f;

#pragma unroll 2
    for (int j = 0; j < H_; ++j) {
        const float4* r4 = (const float4*)(sP1 + j * P1S);
        float t0 = 0.f, t1 = 0.f, t2 = 0.f, t3 = 0.f;
#pragma unroll
        for (int q = 0; q < 16; ++q) {
            float4 wv = r4[q];
            t0 = fmaf(g2acc[4*q+0], wv.x, t0);
            t1 = fmaf(g2acc[4*q+1], wv.y, t1);
            t2 = fmaf(g2acc[4*q+2], wv.z, t2);
            t3 = fmaf(g2acc[4*q+3], wv.w, t3);
        }
        float g3j = ((t0 + t2) + (t1 + t3)) * (((m0 >> j) & 1ull) ? 1.0f : SLOPE_);
        float4 wa = r4[16], wb = r4[17], wc = r4[18], wd = r4[19];
        float wtx = r4[20].x;
        jac[0]  = fmaf(g3j, wa.x, jac[0]);  jac[1]  = fmaf(g3j, wa.y, jac[1]);
        jac[2]  = fmaf(g3j, wa.z, jac[2]);  jac[3]  = fmaf(g3j, wa.w, jac[3]);
        jac[4]  = fmaf(g3j, wb.x, jac[4]);  jac[5]  = fmaf(g3j, wb.y, jac[5]);
        jac[6]  = fmaf(g3j, wb.z, jac[6]);  jac[7]  = fmaf(g3j, wb.w, jac[7]);
        jac[8]  = fmaf(g3j, wc.x, jac[8]);  jac[9]  = fmaf(g3j, wc.y, jac[9]);
        jac[10] = fmaf(g3j, wc.z, jac[10]); jac[11] = fmaf(g3j, wc.w, jac[11]);
        jac[12] = fmaf(g3j, wd.x, jac[12]); jac[13] = fmaf(g3j, wd.y, jac[13]);
        jac[14] = fmaf(g3j, wd.z, jac[14]); jac[15] = fmaf(g3j, wd.w, jac[15]);
        jac[16] = fmaf(g3j, wtx,  jac[16]);
    }

    // hist_jac[d][n][0..15]
    float4* hj = (float4*)(out + HJ_OFF + (d * N_ + n) * 16);
    hj[0] = make_float4(jac[0],  jac[1],  jac[2],  jac[3]);
    hj[1] = make_float4(jac[4],  jac[5],  jac[6],  jac[7]);
    hj[2] = make_float4(jac[8],  jac[9],  jac[10], jac[11]);
    hj[3] = make_float4(jac[12], jac[13], jac[14], jac[15]);

    // logdet: wave reduce then one atomic per block into out[LOG_OFF + b]
    float ld = logf(fabsf(jac[16]));
#pragma unroll
    for (int off = 32; off > 0; off >>= 1)
        ld += __shfl_down(ld, off, 64);

    const int lane = threadIdx.x & 63;
    const int wv   = threadIdx.x >> 6;
    if (lane == 0) red[wv] = ld;
    __syncthreads();
    if (threadIdx.x == 0)
        atomicAdd(out + LOG_OFF + b, (red[0] + red[1]) + (red[2] + red[3]));
}

extern "C" void kernel_launch(void* const* d_in, const int* in_sizes, int n_in,
                              void* d_out, int out_size, void* d_ws, size_t ws_size,
                              hipStream_t stream) {
    const float* x  = (const float*)d_in[0];
    const float* W0 = (const float*)d_in[1];
    const float* b0 = (const float*)d_in[2];
    const float* W1 = (const float*)d_in[3];
    const float* b1 = (const float*)d_in[4];
    const float* W2 = (const float*)d_in[5];
    const float* b2 = (const float*)d_in[6];
    const float* Wo = (const float*)d_in[7];
    const float* bo = (const float*)d_in[8];
    float* out = (float*)d_out;
    float* ws  = (float*)d_ws;   // packs: (8*64*84 + 8*64*68)*4 = 311 KiB

    hipLaunchKernelGGL(setup_kernel, dim3(D_), dim3(256), 0, stream,
                       W0, b0, W1, W2, b2, Wo, ws, out);
    hipLaunchKernelGGL(mlp_kernel, dim3(D_ * B_ * 2), dim3(256), 0, stream,
                       x, b1, bo, ws, out);
}